// Round 4
// baseline (16.273 us; speedup 1.0000x reference)
//
#include <hip/hip_runtime.h>

// The entire reference computation collapses: exp(y - y) == 1 for all finite y,
// so output == sigmoid(SCALE * 1) == sigmoid(2.0) everywhere. The conv is dead.
// Pure constant-fill of 16*64*128*128 floats = 64 MiB of writes.
//
// Round 3 -> 4: the output is one repeated 32-bit pattern -> delegate to
// hipMemsetD32Async, which dispatches ROCm's fillBufferAligned (measured at
// 6.6-6.8 TB/s = 85% of peak on this chip, vs 4.1 TB/s for our hand kernel).
// Memset nodes are graph-capturable (the harness captures hipMemsetAsync
// itself for poisoning).

__global__ void fill_const_tail(float* __restrict__ out, int start, int n, float val) {
    int i = start + blockIdx.x * blockDim.x + threadIdx.x;
    if (i < n) out[i] = val;
}

extern "C" void kernel_launch(void* const* d_in, const int* in_sizes, int n_in,
                              void* d_out, int out_size, void* d_ws, size_t ws_size,
                              hipStream_t stream) {
    // sigmoid(2.0) computed in double, rounded to float
    union { float f; unsigned int u; } cv;
    cv.f = (float)(1.0 / (1.0 + exp(-2.0)));  // 0.8807970779778823f

    // Fill out_size 32-bit words with the constant's bit pattern.
    hipMemsetD32Async((hipDeviceptr_t)d_out, (int)cv.u, (size_t)out_size, stream);
}